// Round 10
// baseline (353.360 us; speedup 1.0000x reference)
//
#include <hip/hip_runtime.h>
#include <math.h>

// TGV-2 PDHG, B=2, H=W=256, T=128.
// R10: 16-launch trapezoid (halo 8), but each block now processes BOTH batch
// images (z=0 and z=1) at the same tile position: tile 16x16, region 32x32,
// 256 blocks (all CUs), 512 threads (8 waves), each thread owns a 1x2 strip
// in each image (two independent v2f streams). The two streams share the 2
// barriers/iter, halving barrier cost per pixel and giving the scheduler two
// independent DS-read->VALU chains after each barrier (sum->max pipe overlap;
// R9 was phase-locked at ~sum). Redundancy 3.0->4.0 is the price; overlap
// should more than cover it.
// Carried from R9: packed v_pk_f32 math, 0/1 mask multipliers, rsq+min
// projection, vb1/vb2 interleaved LDS pair, init folded into launch 0,
// final launch stores only u.

namespace {

typedef float v2f __attribute__((ext_vector_type(2)));

constexpr int kN = 2 * 256 * 256;
constexpr float kTau = 0.28867513459481287f;  // 1/sqrt(12) (f32)
constexpr float kSigma = kTau;
constexpr float kInv1pTau = 1.0f / (1.0f + kTau);

constexpr int RR = 32;          // region rows (H)
constexpr int RC = 32;          // region cols (W)
constexpr int A = RR * RC;      // 1024 floats per LDS array
constexpr int PAD = 64;         // rim-overread safety pads (front/back)
constexpr int TILE = 16;
constexpr int HALO = 8;         // = iterations per launch
constexpr int NLAUNCH = 128 / HALO;      // 16
constexpr int NTHREADS = RR * (RC / 2);  // 512 = 8 waves

__device__ __forceinline__ float4 ld4(const float* p) {
  return *reinterpret_cast<const float4*>(p);
}

// ws layout: 10 arrays of kN floats: ub, v1, v2, vb1, vb2, p1, p2, q11, q22, q12
__global__ __launch_bounds__(NTHREADS, 2) void tgv8_kernel(
    const float* __restrict__ f, const float* __restrict__ rp,
    float* __restrict__ ug, float* __restrict__ ws, int t0) {
  float* ubg = ws + 0 * kN;
  float* v1g = ws + 1 * kN;
  float* v2g = ws + 2 * kN;
  float* vb1g = ws + 3 * kN;
  float* vb2g = ws + 4 * kN;
  float* p1g = ws + 5 * kN;
  float* p2g = ws + 6 * kN;
  float* q11g = ws + 7 * kN;
  float* q22g = ws + 8 * kN;
  float* q12g = ws + 9 * kN;

  // Per tile: ub (A) + vb-pair (2A) + p1,p2,q11,q22,q12 (5A) = 8A floats.
  // Two tiles (z=0,1) back to back.
  __shared__ __align__(16) float smem[PAD + 16 * A + PAD];

  const int tid = threadIdx.x;
  const int r = tid >> 4;        // region row 0..31
  const int c = (tid & 15) * 2;  // region col (float2-aligned)
  const int rc = r * RC + c;

  const int gi = blockIdx.y * TILE + r - HALO;  // global row (may be OOB)
  const int gj = blockIdx.x * TILE + c - HALO;  // global col (even)
  const bool inImg = ((unsigned)gi < 256u) && ((unsigned)gj < 256u);
  const int base0 = gi * 256 + gj;  // z=0; z=1 at +65536

  const float alpha0 = rp[0];
  const float alpha1 = rp[1];

  // ---- boundary masks as 0/1 multipliers (shared by both images) ----
  const float mD = (gi != 255) ? 1.f : 0.f;  // has down neighbor (H fwd)
  const float mU = (gi != 0) ? 1.f : 0.f;    // has up neighbor (H bwd)
  v2f mR, mL;
  mR.x = (gj + 0 != 255) ? 1.f : 0.f;
  mR.y = (gj + 1 != 255) ? 1.f : 0.f;
  mL.x = (gj != 0) ? 1.f : 0.f;
  mL.y = 1.f;

  // state: one packed v2f per field per image
  v2f u_[2], ub_[2], v1_[2], v2_[2], vb1_[2], vb2_[2];
  v2f p1_[2], p2_[2], q11_[2], q22_[2], q12_[2], f_[2];

#define LOADV(dst, src) dst = *reinterpret_cast<const v2f*>((src) + base);
#pragma unroll
  for (int z = 0; z < 2; ++z) {
    const int base = base0 + z * 65536;
    if (inImg) {
      LOADV(f_[z], f)
      if (t0 == 0) {
        u_[z] = f_[z]; ub_[z] = f_[z];
        v1_[z] = 0.f; v2_[z] = 0.f; vb1_[z] = 0.f; vb2_[z] = 0.f;
        p1_[z] = 0.f; p2_[z] = 0.f;
        q11_[z] = 0.f; q22_[z] = 0.f; q12_[z] = 0.f;
      } else {
        LOADV(u_[z], ug)
        LOADV(ub_[z], ubg)
        LOADV(v1_[z], v1g)
        LOADV(v2_[z], v2g)
        LOADV(vb1_[z], vb1g)
        LOADV(vb2_[z], vb2g)
        LOADV(p1_[z], p1g)
        LOADV(p2_[z], p2g)
        LOADV(q11_[z], q11g)
        LOADV(q22_[z], q22g)
        LOADV(q12_[z], q12g)
      }
    } else {
      f_[z] = 0.f; u_[z] = 0.f; ub_[z] = 0.f;
      v1_[z] = 0.f; v2_[z] = 0.f; vb1_[z] = 0.f; vb2_[z] = 0.f;
      p1_[z] = 0.f; p2_[z] = 0.f; q11_[z] = 0.f; q22_[z] = 0.f; q12_[z] = 0.f;
    }
  }
#undef LOADV

  for (int t = 0; t < HALO; ++t) {
    // ---- publish dual halos: ub (b64), vb pair (b128), both images ----
#pragma unroll
    for (int z = 0; z < 2; ++z) {
      float* ubS = smem + PAD + z * 8 * A;
      float* vbS = ubS + A;
      *reinterpret_cast<v2f*>(ubS + rc) = ub_[z];
      float4 vp;
      vp.x = vb1_[z].x; vp.y = vb2_[z].x; vp.z = vb1_[z].y; vp.w = vb2_[z].y;
      *reinterpret_cast<float4*>(vbS + 2 * rc) = vp;
    }
    __syncthreads();

    // ---- dual ascent + projections (two independent streams) ----
#pragma unroll
    for (int z = 0; z < 2; ++z) {
      float* ubS = smem + PAD + z * 8 * A;
      float* vbS = ubS + A;

      const float ubX = ubS[rc + 2];  // right-edge scalar neighbor
      const v2f vbX = *reinterpret_cast<const v2f*>(vbS + 2 * (rc + 2));
      const v2f ubD = *reinterpret_cast<const v2f*>(ubS + rc + RC);
      const float4 vd = ld4(vbS + 2 * (rc + RC));
      v2f vb1D, vb2D;
      vb1D.x = vd.x; vb1D.y = vd.z;
      vb2D.x = vd.y; vb2D.y = vd.w;

      v2f ubr, vb1r, vb2r;  // right-shifted (element e+1)
      ubr.x = ub_[z].y;   ubr.y = ubX;
      vb1r.x = vb1_[z].y; vb1r.y = vbX.x;
      vb2r.x = vb2_[z].y; vb2r.y = vbX.y;

      // p update
      const v2f du1 = mD * (ubD - ub_[z]);
      const v2f du2 = mR * (ubr - ub_[z]);
      const v2f pn1 = p1_[z] + kSigma * (du1 - vb1_[z]);
      const v2f pn2 = p2_[z] + kSigma * (du2 - vb2_[z]);
      const v2f n2p = pn1 * pn1 + pn2 * pn2;
      v2f sp;
      sp.x = fminf(1.f, alpha1 * __builtin_amdgcn_rsqf(n2p.x));
      sp.y = fminf(1.f, alpha1 * __builtin_amdgcn_rsqf(n2p.y));
      p1_[z] = pn1 * sp;
      p2_[z] = pn2 * sp;

      // q update (e11, e22, e12)
      const v2f e11 = mD * (vb1D - vb1_[z]);
      const v2f e22 = mR * (vb2r - vb2_[z]);
      const v2f e12 = 0.5f * (mR * (vb1r - vb1_[z]) + mD * (vb2D - vb2_[z]));
      const v2f qn1 = q11_[z] + kSigma * e11;
      const v2f qn2 = q22_[z] + kSigma * e22;
      const v2f qn3 = q12_[z] + kSigma * e12;
      const v2f n2q = qn1 * qn1 + qn2 * qn2 + 2.f * (qn3 * qn3);
      v2f sq;
      sq.x = fminf(1.f, alpha0 * __builtin_amdgcn_rsqf(n2q.x));
      sq.y = fminf(1.f, alpha0 * __builtin_amdgcn_rsqf(n2q.y));
      q11_[z] = qn1 * sq;
      q22_[z] = qn2 * sq;
      q12_[z] = qn3 * sq;
    }

    // ---- publish primal halos (new p, q), both images ----
#pragma unroll
    for (int z = 0; z < 2; ++z) {
      float* ubS = smem + PAD + z * 8 * A;
      float* p1S = ubS + 3 * A;
      float* p2S = p1S + A;
      float* q11S = p2S + A;
      float* q22S = q11S + A;
      float* q12S = q22S + A;
      *reinterpret_cast<v2f*>(p1S + rc) = p1_[z];
      *reinterpret_cast<v2f*>(p2S + rc) = p2_[z];
      *reinterpret_cast<v2f*>(q11S + rc) = q11_[z];
      *reinterpret_cast<v2f*>(q22S + rc) = q22_[z];
      *reinterpret_cast<v2f*>(q12S + rc) = q12_[z];
    }
    __syncthreads();

    // ---- primal descent + over-relaxation (two independent streams) ----
#pragma unroll
    for (int z = 0; z < 2; ++z) {
      float* ubS = smem + PAD + z * 8 * A;
      float* p1S = ubS + 3 * A;
      float* p2S = p1S + A;
      float* q11S = p2S + A;
      float* q22S = q11S + A;
      float* q12S = q22S + A;

      const v2f p1U = *reinterpret_cast<const v2f*>(p1S + rc - RC);
      const v2f q11U = *reinterpret_cast<const v2f*>(q11S + rc - RC);
      const v2f q12U = *reinterpret_cast<const v2f*>(q12S + rc - RC);
      const float p2Ls = p2S[rc - 1];   // left-edge scalar neighbors
      const float q22Ls = q22S[rc - 1];
      const float q12Ls = q12S[rc - 1];

      v2f p2l, q22l, q12l;  // left-shifted (element e-1)
      p2l.x = p2Ls;   p2l.y = p2_[z].x;
      q22l.x = q22Ls; q22l.y = q22_[z].x;
      q12l.x = q12Ls; q12l.y = q12_[z].x;

      const v2f divp = mD * p1_[z] + mR * p2_[z] - (mU * p1U + mL * p2l);
      const v2f un = (u_[z] + kTau * divp + kTau * f_[z]) * kInv1pTau;
      ub_[z] = 2.f * un - u_[z];
      u_[z] = un;

      const v2f c1 = mD * q11_[z] + mR * q12_[z] - (mU * q11U + mL * q12l);
      const v2f c2 = mD * q12_[z] + mR * q22_[z] - (mU * q12U + mL * q22l);
      const v2f v1n = v1_[z] + kTau * (p1_[z] + c1);
      const v2f v2n = v2_[z] + kTau * (p2_[z] + c2);
      vb1_[z] = 2.f * v1n - v1_[z];
      v1_[z] = v1n;
      vb2_[z] = 2.f * v2n - v2_[z];
      v2_[z] = v2n;
    }
  }

  // ---- store interior 16x16 per image (exact after 8 iters) ----
  if (r >= HALO && r < HALO + TILE && c >= HALO && c < HALO + TILE) {
#define STOREV(src, dst) *reinterpret_cast<v2f*>((dst) + base) = src;
#pragma unroll
    for (int z = 0; z < 2; ++z) {
      const int base = base0 + z * 65536;
      STOREV(u_[z], ug)
      if (t0 != NLAUNCH - 1) {  // ws is dead after the final launch
        STOREV(ub_[z], ubg)
        STOREV(v1_[z], v1g)
        STOREV(v2_[z], v2g)
        STOREV(vb1_[z], vb1g)
        STOREV(vb2_[z], vb2g)
        STOREV(p1_[z], p1g)
        STOREV(p2_[z], p2g)
        STOREV(q11_[z], q11g)
        STOREV(q22_[z], q22g)
        STOREV(q12_[z], q12g)
      }
    }
#undef STOREV
  }
}

}  // namespace

extern "C" void kernel_launch(void* const* d_in, const int* in_sizes, int n_in,
                              void* d_out, int out_size, void* d_ws,
                              size_t ws_size, hipStream_t stream) {
  const float* f = (const float*)d_in[0];
  const float* rp = (const float*)d_in[1];  // [alpha0, alpha1]
  // d_in[2] is T = 128 (fixed; trip count must be static for graph capture).

  float* u = (float*)d_out;
  float* ws = (float*)d_ws;

  dim3 grid(256 / TILE, 256 / TILE, 1);  // 16 x 16 = 256 blocks, both z inside
  for (int t = 0; t < NLAUNCH; ++t) {    // 16 launches x 8 iterations
    hipLaunchKernelGGL(tgv8_kernel, grid, dim3(NTHREADS), 0, stream, f, rp, u,
                       ws, t);
  }
}

// Round 11
// 302.573 us; speedup vs baseline: 1.1679x; 1.1679x over previous
//
#include <hip/hip_runtime.h>
#include <math.h>

// TGV-2 PDHG, B=2, H=W=256, T=128.
// R11: register-patch trapezoid. R10's failure quantified the regime: time
// scales with (DS instr per px) x redundancy -> LDS-pipe-throughput-bound
// (R9: ~1430 LDS cyc/iter/CU vs ~390 VALU). So cut DS/px: each thread owns a
// 4-row x 2-col patch; interior neighbors are in registers; LDS carries only
// patch-boundary exchanges in packed arrays (rows: b64/b128; cols stored
// contiguously per (patch-col, row-block) -> b128). 20 DS instr per 8 px
// = 2.5/px vs R9's 8.5/px.
// Geometry: 16 launches x 8 iters, tile 16x32, halo 8, region 32x48
// (redundancy 3.0), 256 blocks (1/CU), 192 threads (3 waves; low occupancy
// accepted - pipes fed by within-thread ILP across 4 rows x 12 fields).
// Carried: packed v2f math, 0/1 mask multipliers (now per-row for H),
// rsq+min projection, init folded into launch 0, final launch stores only u.

namespace {

typedef float v2f __attribute__((ext_vector_type(2)));

constexpr int kN = 2 * 256 * 256;
constexpr float kTau = 0.28867513459481287f;  // 1/sqrt(12) (f32)
constexpr float kSigma = kTau;
constexpr float kInv1pTau = 1.0f / (1.0f + kTau);

constexpr int TILE_R = 16;
constexpr int TILE_C = 32;
constexpr int HALO = 8;              // = iterations per launch
constexpr int NLAUNCH = 128 / HALO;  // 16
constexpr int NPR = 8;               // patch-rows  (32 region rows / 4)
constexpr int NPC = 24;              // patch-cols  (48 region cols / 2)
constexpr int NTHREADS = NPR * NPC;  // 192 = 3 waves

// LDS float offsets (all 16B aligned)
constexpr int O_RXU = 0;                   // rowXub  [9*48]      dual ub top row
constexpr int O_RXV = O_RXU + 9 * 48;      // rowXvb  [9*96]      dual vb top row
constexpr int O_CXU = O_RXV + 9 * 96;      // colXub  [8*25*4]    dual ub left col
constexpr int O_CXV = O_CXU + 8 * 25 * 4;  // colXvb  [8*25*8]    dual vb left col
constexpr int O_RPP = O_CXV + 8 * 25 * 8;  // rowPpq  [9*96]      primal (p1,q11) bottom row
constexpr int O_RPQ = O_RPP + 9 * 96;      // rowPq12 [9*48]      primal q12 bottom row
constexpr int O_CPP = O_RPQ + 9 * 48;      // colPpq  [8*25*8]    primal (p2,q22) right col
constexpr int O_CPQ = O_CPP + 8 * 25 * 8;  // colPq12 [8*25*4]    primal q12 right col
constexpr int LDS_FLOATS = O_CPQ + 8 * 25 * 4;  // 7392 floats = 29.6 KB

__global__ __launch_bounds__(NTHREADS, 1) void tgv8_kernel(
    const float* __restrict__ f, const float* __restrict__ rp,
    float* __restrict__ ug, float* __restrict__ ws, int t0) {
  float* ubg = ws + 0 * kN;
  float* v1g = ws + 1 * kN;
  float* v2g = ws + 2 * kN;
  float* vb1g = ws + 3 * kN;
  float* vb2g = ws + 4 * kN;
  float* p1g = ws + 5 * kN;
  float* p2g = ws + 6 * kN;
  float* q11g = ws + 7 * kN;
  float* q22g = ws + 8 * kN;
  float* q12g = ws + 9 * kN;

  __shared__ __align__(16) float smem[LDS_FLOATS];
  float* rowXub = smem + O_RXU;
  float* rowXvb = smem + O_RXV;
  float* colXub = smem + O_CXU;
  float* colXvb = smem + O_CXV;
  float* rowPpq = smem + O_RPP;
  float* rowPq12 = smem + O_RPQ;
  float* colPpq = smem + O_CPP;
  float* colPq12 = smem + O_CPQ;

  const int tid = threadIdx.x;
  const int pr = tid / NPC;        // patch-row 0..7  (rows pr*4 .. pr*4+3)
  const int pc = tid % NPC;        // patch-col 0..23 (cols pc*2, pc*2+1)
  const int c0 = pc * 2;

  const int gi0 = blockIdx.y * TILE_R + pr * 4 - HALO;  // global row of patch row 0
  const int gj = blockIdx.x * TILE_C + c0 - HALO;       // global col (even)
  const bool colsIn = ((unsigned)gj < 256u);            // gj even => gj+1 in too
  const int zb = blockIdx.z * 65536;

  const float alpha0 = rp[0];
  const float alpha1 = rp[1];

  // ---- boundary masks (per-row for H, per-col-pair for W) ----
  float mDr[4], mUr[4];
#pragma unroll
  for (int k = 0; k < 4; ++k) {
    mDr[k] = (gi0 + k != 255) ? 1.f : 0.f;
    mUr[k] = (gi0 + k != 0) ? 1.f : 0.f;
  }
  v2f mR, mL;
  mR.x = (gj + 0 != 255) ? 1.f : 0.f;
  mR.y = (gj + 1 != 255) ? 1.f : 0.f;
  mL.x = (gj != 0) ? 1.f : 0.f;
  mL.y = 1.f;

  // state: one v2f per field per patch row
  v2f u_[4], ub_[4], v1_[4], v2_[4], vb1_[4], vb2_[4];
  v2f p1_[4], p2_[4], q11_[4], q22_[4], q12_[4], f_[4];

#pragma unroll
  for (int k = 0; k < 4; ++k) {
    f_[k] = 0.f; u_[k] = 0.f; ub_[k] = 0.f;
    v1_[k] = 0.f; v2_[k] = 0.f; vb1_[k] = 0.f; vb2_[k] = 0.f;
    p1_[k] = 0.f; p2_[k] = 0.f; q11_[k] = 0.f; q22_[k] = 0.f; q12_[k] = 0.f;
  }
#define LDV(ptr) (*reinterpret_cast<const v2f*>(ptr))
#pragma unroll
  for (int k = 0; k < 4; ++k) {
    if (colsIn && ((unsigned)(gi0 + k) < 256u)) {
      const int b = zb + (gi0 + k) * 256 + gj;
      f_[k] = LDV(f + b);
      if (t0 == 0) {
        u_[k] = f_[k];
        ub_[k] = f_[k];
      } else {
        u_[k] = LDV(ug + b);
        ub_[k] = LDV(ubg + b);
        v1_[k] = LDV(v1g + b);
        v2_[k] = LDV(v2g + b);
        vb1_[k] = LDV(vb1g + b);
        vb2_[k] = LDV(vb2g + b);
        p1_[k] = LDV(p1g + b);
        p2_[k] = LDV(p2g + b);
        q11_[k] = LDV(q11g + b);
        q22_[k] = LDV(q22g + b);
        q12_[k] = LDV(q12g + b);
      }
    }
  }
#undef LDV

  for (int t = 0; t < HALO; ++t) {
    // ======== dual phase ========
    // publish: top row (consumed by patch above as its row r0+4),
    //          left col (consumed by patch to the left as its col c0+2)
    *reinterpret_cast<v2f*>(rowXub + pr * 48 + c0) = ub_[0];
    {
      float4 t4;
      t4.x = vb1_[0].x; t4.y = vb2_[0].x; t4.z = vb1_[0].y; t4.w = vb2_[0].y;
      *reinterpret_cast<float4*>(rowXvb + pr * 96 + c0 * 2) = t4;
    }
    {
      float4 t4;
      t4.x = ub_[0].x; t4.y = ub_[1].x; t4.z = ub_[2].x; t4.w = ub_[3].x;
      *reinterpret_cast<float4*>(colXub + (pr * 25 + pc) * 4) = t4;
    }
    {
      float4 a, b;
      a.x = vb1_[0].x; a.y = vb2_[0].x; a.z = vb1_[1].x; a.w = vb2_[1].x;
      b.x = vb1_[2].x; b.y = vb2_[2].x; b.z = vb1_[3].x; b.w = vb2_[3].x;
      *reinterpret_cast<float4*>(colXvb + (pr * 25 + pc) * 8) = a;
      *reinterpret_cast<float4*>(colXvb + (pr * 25 + pc) * 8 + 4) = b;
    }
    __syncthreads();

    const v2f ubDn = *reinterpret_cast<const v2f*>(rowXub + (pr + 1) * 48 + c0);
    const float4 vbDn =
        *reinterpret_cast<const float4*>(rowXvb + (pr + 1) * 96 + c0 * 2);
    const float4 ubR =
        *reinterpret_cast<const float4*>(colXub + (pr * 25 + pc + 1) * 4);
    const float4 vbRa =
        *reinterpret_cast<const float4*>(colXvb + (pr * 25 + pc + 1) * 8);
    const float4 vbRb =
        *reinterpret_cast<const float4*>(colXvb + (pr * 25 + pc + 1) * 8 + 4);

#pragma unroll
    for (int k = 0; k < 4; ++k) {
      v2f ubD, v1D, v2D;
      if (k < 3) {
        ubD = ub_[k + 1]; v1D = vb1_[k + 1]; v2D = vb2_[k + 1];
      } else {
        ubD.x = ubDn.x; ubD.y = ubDn.y;
        v1D.x = vbDn.x; v1D.y = vbDn.z;
        v2D.x = vbDn.y; v2D.y = vbDn.w;
      }
      const float ubRk = (&ubR.x)[k];
      const float vb1Rk = (k == 0) ? vbRa.x : (k == 1) ? vbRa.z
                          : (k == 2) ? vbRb.x : vbRb.z;
      const float vb2Rk = (k == 0) ? vbRa.y : (k == 1) ? vbRa.w
                          : (k == 2) ? vbRb.y : vbRb.w;
      v2f ubr, vb1r, vb2r;
      ubr.x = ub_[k].y;   ubr.y = ubRk;
      vb1r.x = vb1_[k].y; vb1r.y = vb1Rk;
      vb2r.x = vb2_[k].y; vb2r.y = vb2Rk;

      // p update
      const v2f du1 = mDr[k] * (ubD - ub_[k]);
      const v2f du2 = mR * (ubr - ub_[k]);
      const v2f pn1 = p1_[k] + kSigma * (du1 - vb1_[k]);
      const v2f pn2 = p2_[k] + kSigma * (du2 - vb2_[k]);
      const v2f n2p = pn1 * pn1 + pn2 * pn2;
      v2f sp;
      sp.x = fminf(1.f, alpha1 * __builtin_amdgcn_rsqf(n2p.x));
      sp.y = fminf(1.f, alpha1 * __builtin_amdgcn_rsqf(n2p.y));
      p1_[k] = pn1 * sp;
      p2_[k] = pn2 * sp;

      // q update
      const v2f e11 = mDr[k] * (v1D - vb1_[k]);
      const v2f e22 = mR * (vb2r - vb2_[k]);
      const v2f e12 = 0.5f * (mR * (vb1r - vb1_[k]) + mDr[k] * (v2D - vb2_[k]));
      const v2f qn1 = q11_[k] + kSigma * e11;
      const v2f qn2 = q22_[k] + kSigma * e22;
      const v2f qn3 = q12_[k] + kSigma * e12;
      const v2f n2q = qn1 * qn1 + qn2 * qn2 + 2.f * (qn3 * qn3);
      v2f sq;
      sq.x = fminf(1.f, alpha0 * __builtin_amdgcn_rsqf(n2q.x));
      sq.y = fminf(1.f, alpha0 * __builtin_amdgcn_rsqf(n2q.y));
      q11_[k] = qn1 * sq;
      q22_[k] = qn2 * sq;
      q12_[k] = qn3 * sq;
    }

    // ======== primal phase ========
    // publish: bottom row (consumed by patch below as its row r0-1),
    //          right col (consumed by patch to the right as its col c0-1)
    {
      float4 t4;
      t4.x = p1_[3].x; t4.y = q11_[3].x; t4.z = p1_[3].y; t4.w = q11_[3].y;
      *reinterpret_cast<float4*>(rowPpq + (pr + 1) * 96 + c0 * 2) = t4;
    }
    *reinterpret_cast<v2f*>(rowPq12 + (pr + 1) * 48 + c0) = q12_[3];
    {
      float4 a, b;
      a.x = p2_[0].y; a.y = q22_[0].y; a.z = p2_[1].y; a.w = q22_[1].y;
      b.x = p2_[2].y; b.y = q22_[2].y; b.z = p2_[3].y; b.w = q22_[3].y;
      *reinterpret_cast<float4*>(colPpq + (pr * 25 + pc + 1) * 8) = a;
      *reinterpret_cast<float4*>(colPpq + (pr * 25 + pc + 1) * 8 + 4) = b;
    }
    {
      float4 t4;
      t4.x = q12_[0].y; t4.y = q12_[1].y; t4.z = q12_[2].y; t4.w = q12_[3].y;
      *reinterpret_cast<float4*>(colPq12 + (pr * 25 + pc + 1) * 4) = t4;
    }
    __syncthreads();

    const float4 pqU =
        *reinterpret_cast<const float4*>(rowPpq + pr * 96 + c0 * 2);
    const v2f q12U0 = *reinterpret_cast<const v2f*>(rowPq12 + pr * 48 + c0);
    const float4 pqLa =
        *reinterpret_cast<const float4*>(colPpq + (pr * 25 + pc) * 8);
    const float4 pqLb =
        *reinterpret_cast<const float4*>(colPpq + (pr * 25 + pc) * 8 + 4);
    const float4 q12L =
        *reinterpret_cast<const float4*>(colPq12 + (pr * 25 + pc) * 4);

#pragma unroll
    for (int k = 0; k < 4; ++k) {
      v2f p1U, q11U, q12Uk;
      if (k > 0) {
        p1U = p1_[k - 1]; q11U = q11_[k - 1]; q12Uk = q12_[k - 1];
      } else {
        p1U.x = pqU.x;  p1U.y = pqU.z;
        q11U.x = pqU.y; q11U.y = pqU.w;
        q12Uk = q12U0;
      }
      const float p2Lk = (k == 0) ? pqLa.x : (k == 1) ? pqLa.z
                         : (k == 2) ? pqLb.x : pqLb.z;
      const float q22Lk = (k == 0) ? pqLa.y : (k == 1) ? pqLa.w
                          : (k == 2) ? pqLb.y : pqLb.w;
      const float q12Lk = (&q12L.x)[k];
      v2f p2l, q22l, q12l;
      p2l.x = p2Lk;   p2l.y = p2_[k].x;
      q22l.x = q22Lk; q22l.y = q22_[k].x;
      q12l.x = q12Lk; q12l.y = q12_[k].x;

      const v2f divp = mDr[k] * p1_[k] + mR * p2_[k] - (mUr[k] * p1U + mL * p2l);
      const v2f un = (u_[k] + kTau * divp + kTau * f_[k]) * kInv1pTau;
      ub_[k] = 2.f * un - u_[k];
      u_[k] = un;

      const v2f c1 =
          mDr[k] * q11_[k] + mR * q12_[k] - (mUr[k] * q11U + mL * q12l);
      const v2f c2 =
          mDr[k] * q12_[k] + mR * q22_[k] - (mUr[k] * q12Uk + mL * q22l);
      const v2f v1n = v1_[k] + kTau * (p1_[k] + c1);
      const v2f v2n = v2_[k] + kTau * (p2_[k] + c2);
      vb1_[k] = 2.f * v1n - v1_[k];
      v1_[k] = v1n;
      vb2_[k] = 2.f * v2n - v2_[k];
      v2_[k] = v2n;
    }
  }

  // ---- store interior 16x32 (patch-aligned: pr 2..5, pc 4..19) ----
  if (pr >= 2 && pr < 6 && pc >= 4 && pc < 20) {
#define STV(src, dst) *reinterpret_cast<v2f*>((dst) + b) = src;
#pragma unroll
    for (int k = 0; k < 4; ++k) {
      const int b = zb + (gi0 + k) * 256 + gj;
      STV(u_[k], ug)
      if (t0 != NLAUNCH - 1) {  // ws is dead after the final launch
        STV(ub_[k], ubg)
        STV(v1_[k], v1g)
        STV(v2_[k], v2g)
        STV(vb1_[k], vb1g)
        STV(vb2_[k], vb2g)
        STV(p1_[k], p1g)
        STV(p2_[k], p2g)
        STV(q11_[k], q11g)
        STV(q22_[k], q22g)
        STV(q12_[k], q12g)
      }
    }
#undef STV
  }
}

}  // namespace

extern "C" void kernel_launch(void* const* d_in, const int* in_sizes, int n_in,
                              void* d_out, int out_size, void* d_ws,
                              size_t ws_size, hipStream_t stream) {
  const float* f = (const float*)d_in[0];
  const float* rp = (const float*)d_in[1];  // [alpha0, alpha1]
  // d_in[2] is T = 128 (fixed; trip count must be static for graph capture).

  float* u = (float*)d_out;
  float* ws = (float*)d_ws;

  dim3 grid(256 / TILE_C, 256 / TILE_R, 2);  // 8 x 16 x 2 = 256 blocks
  for (int t = 0; t < NLAUNCH; ++t) {        // 16 launches x 8 iterations
    hipLaunchKernelGGL(tgv8_kernel, grid, dim3(NTHREADS), 0, stream, f, rp, u,
                       ws, t);
  }
}

// Round 12
// 261.471 us; speedup vs baseline: 1.3514x; 1.1572x over previous
//
#include <hip/hip_runtime.h>
#include <math.h>

// TGV-2 PDHG, B=2, H=W=256, T=128.
// R12 = R9 (best: 255.8us; 16-launch trapezoid, region 32x48, tile 16x32,
// halo 8, 256 blocks = 1/CU, 768 threads = 12 waves, 1x2 strips, packed
// v_pk_f32 math, 0/1 mask multipliers, rsq+min projection, vb1/vb2
// interleaved LDS pair, init folded into launch 0, final launch stores only
// u) + packed PRIMAL exchange:
//   pqA = (p1,q11) interleaved per px, pqB = (p2,q22) interleaved per px.
//   publishes 5->3 (2xb128 + b64), up-reads 3->2 (b128+b64), left-reads
//   3->2 (one b64 pair read gives both p2,q22 scalars; q12 b32).
// DS instr/thread-iter 17->13. Bank pattern stays linear (stride-2-float
// arrays validated by vbS in R9).
// Failed paths (do not revisit): persistent kernels (XCD-coherence fences
// -> 160MB HBM refetch, R4-R6); batch-pairing in one block (redundancy
// dominates, R10); register patches at 3 waves (occupancy floor, R11).

namespace {

typedef float v2f __attribute__((ext_vector_type(2)));

constexpr int kN = 2 * 256 * 256;
constexpr float kTau = 0.28867513459481287f;  // 1/sqrt(12) (f32)
constexpr float kSigma = kTau;
constexpr float kInv1pTau = 1.0f / (1.0f + kTau);

constexpr int RR = 32;          // region rows (H)
constexpr int RC = 48;          // region cols (W)
constexpr int A = RR * RC;      // 1536 floats per LDS array
constexpr int PAD = 64;         // rim-overread safety pads (front/back)
constexpr int TILE_R = 16;
constexpr int TILE_C = 32;
constexpr int HALO = 8;         // = iterations per launch
constexpr int NLAUNCH = 128 / HALO;      // 16
constexpr int NTHREADS = RR * (RC / 2);  // 768 = 12 waves

__device__ __forceinline__ float4 ld4(const float* p) {
  return *reinterpret_cast<const float4*>(p);
}

// ws layout: 10 arrays of kN floats: ub, v1, v2, vb1, vb2, p1, p2, q11, q22, q12
__global__ __launch_bounds__(NTHREADS, 3) void tgv8_kernel(
    const float* __restrict__ f, const float* __restrict__ rp,
    float* __restrict__ ug, float* __restrict__ ws, int t0) {
  float* ubg = ws + 0 * kN;
  float* v1g = ws + 1 * kN;
  float* v2g = ws + 2 * kN;
  float* vb1g = ws + 3 * kN;
  float* vb2g = ws + 4 * kN;
  float* p1g = ws + 5 * kN;
  float* p2g = ws + 6 * kN;
  float* q11g = ws + 7 * kN;
  float* q22g = ws + 8 * kN;
  float* q12g = ws + 9 * kN;

  // LDS: ub (A) + vb-pair (2A) + pqA-pair (2A) + pqB-pair (2A) + q12 (A)
  __shared__ __align__(16) float smem[PAD + 8 * A + PAD];
  float* ubS = smem + PAD;
  float* vbS = ubS + A;        // [vb1, vb2] per px
  float* pqAS = vbS + 2 * A;   // [p1, q11] per px
  float* pqBS = pqAS + 2 * A;  // [p2, q22] per px
  float* q12S = pqBS + 2 * A;

  const int tid = threadIdx.x;
  const int r = tid / 24;        // region row 0..31
  const int c = (tid % 24) * 2;  // region col (float2-aligned)
  const int rc = r * RC + c;

  const int gi = blockIdx.y * TILE_R + r - HALO;  // global row (may be OOB)
  const int gj = blockIdx.x * TILE_C + c - HALO;  // global col (even)
  const bool inImg = ((unsigned)gi < 256u) && ((unsigned)gj < 256u);
  const int base = blockIdx.z * 65536 + gi * 256 + gj;

  const float alpha0 = rp[0];
  const float alpha1 = rp[1];

  // ---- boundary masks as 0/1 multipliers (thread-constant) ----
  const float mD = (gi != 255) ? 1.f : 0.f;  // has down neighbor (H fwd)
  const float mU = (gi != 0) ? 1.f : 0.f;    // has up neighbor (H bwd)
  v2f mR, mL;
  mR.x = (gj + 0 != 255) ? 1.f : 0.f;
  mR.y = (gj + 1 != 255) ? 1.f : 0.f;
  mL.x = (gj != 0) ? 1.f : 0.f;
  mL.y = 1.f;

  // state: one packed v2f per field
  v2f u_, ub_, v1_, v2_, vb1_, vb2_, p1_, p2_, q11_, q22_, q12_, f_;

#define LOADV(dst, src) dst = *reinterpret_cast<const v2f*>((src) + base);
  if (inImg) {
    LOADV(f_, f)
    if (t0 == 0) {
      // PDHG initial state: u = ub = f, everything else zero.
      u_ = f_; ub_ = f_;
      v1_ = 0.f; v2_ = 0.f; vb1_ = 0.f; vb2_ = 0.f;
      p1_ = 0.f; p2_ = 0.f; q11_ = 0.f; q22_ = 0.f; q12_ = 0.f;
    } else {
      LOADV(u_, ug)
      LOADV(ub_, ubg)
      LOADV(v1_, v1g)
      LOADV(v2_, v2g)
      LOADV(vb1_, vb1g)
      LOADV(vb2_, vb2g)
      LOADV(p1_, p1g)
      LOADV(p2_, p2g)
      LOADV(q11_, q11g)
      LOADV(q22_, q22g)
      LOADV(q12_, q12g)
    }
  } else {
    f_ = 0.f; u_ = 0.f; ub_ = 0.f;
    v1_ = 0.f; v2_ = 0.f; vb1_ = 0.f; vb2_ = 0.f;
    p1_ = 0.f; p2_ = 0.f; q11_ = 0.f; q22_ = 0.f; q12_ = 0.f;
  }
#undef LOADV

  for (int t = 0; t < HALO; ++t) {
    // ---- publish dual halos: ub (b64), vb pair (b128) ----
    *reinterpret_cast<v2f*>(ubS + rc) = ub_;
    {
      float4 vp;
      vp.x = vb1_.x; vp.y = vb2_.x; vp.z = vb1_.y; vp.w = vb2_.y;
      *reinterpret_cast<float4*>(vbS + 2 * rc) = vp;
    }
    __syncthreads();

    // ---- dual ascent + projections ----
    const float ubX = ubS[rc + 2];  // right-edge scalar neighbor
    const v2f vbX = *reinterpret_cast<const v2f*>(vbS + 2 * (rc + 2));
    const v2f ubD = *reinterpret_cast<const v2f*>(ubS + rc + RC);
    const float4 vd = ld4(vbS + 2 * (rc + RC));
    v2f vb1D, vb2D;
    vb1D.x = vd.x; vb1D.y = vd.z;
    vb2D.x = vd.y; vb2D.y = vd.w;

    v2f ubr, vb1r, vb2r;  // right-shifted (element e+1)
    ubr.x = ub_.y;   ubr.y = ubX;
    vb1r.x = vb1_.y; vb1r.y = vbX.x;
    vb2r.x = vb2_.y; vb2r.y = vbX.y;

    // p update
    const v2f du1 = mD * (ubD - ub_);
    const v2f du2 = mR * (ubr - ub_);
    const v2f pn1 = p1_ + kSigma * (du1 - vb1_);
    const v2f pn2 = p2_ + kSigma * (du2 - vb2_);
    const v2f n2p = pn1 * pn1 + pn2 * pn2;
    v2f sp;
    sp.x = fminf(1.f, alpha1 * __builtin_amdgcn_rsqf(n2p.x));
    sp.y = fminf(1.f, alpha1 * __builtin_amdgcn_rsqf(n2p.y));
    p1_ = pn1 * sp;
    p2_ = pn2 * sp;

    // q update (e11, e22, e12)
    const v2f e11 = mD * (vb1D - vb1_);
    const v2f e22 = mR * (vb2r - vb2_);
    const v2f e12 = 0.5f * (mR * (vb1r - vb1_) + mD * (vb2D - vb2_));
    const v2f qn1 = q11_ + kSigma * e11;
    const v2f qn2 = q22_ + kSigma * e22;
    const v2f qn3 = q12_ + kSigma * e12;
    const v2f n2q = qn1 * qn1 + qn2 * qn2 + 2.f * (qn3 * qn3);
    v2f sq;
    sq.x = fminf(1.f, alpha0 * __builtin_amdgcn_rsqf(n2q.x));
    sq.y = fminf(1.f, alpha0 * __builtin_amdgcn_rsqf(n2q.y));
    q11_ = qn1 * sq;
    q22_ = qn2 * sq;
    q12_ = qn3 * sq;

    // ---- publish primal halos: (p1,q11) b128, (p2,q22) b128, q12 b64 ----
    {
      float4 t4;
      t4.x = p1_.x; t4.y = q11_.x; t4.z = p1_.y; t4.w = q11_.y;
      *reinterpret_cast<float4*>(pqAS + 2 * rc) = t4;
    }
    {
      float4 t4;
      t4.x = p2_.x; t4.y = q22_.x; t4.z = p2_.y; t4.w = q22_.y;
      *reinterpret_cast<float4*>(pqBS + 2 * rc) = t4;
    }
    *reinterpret_cast<v2f*>(q12S + rc) = q12_;
    __syncthreads();

    // ---- primal descent + over-relaxation ----
    const float4 pu = ld4(pqAS + 2 * (rc - RC));  // (p1,q11) up
    v2f p1U, q11U;
    p1U.x = pu.x;  p1U.y = pu.z;
    q11U.x = pu.y; q11U.y = pu.w;
    const v2f q12U = *reinterpret_cast<const v2f*>(q12S + rc - RC);
    const v2f pqL = *reinterpret_cast<const v2f*>(pqBS + 2 * (rc - 1));
    const float p2Ls = pqL.x;   // p2 at (r, c-1)
    const float q22Ls = pqL.y;  // q22 at (r, c-1)
    const float q12Ls = q12S[rc - 1];

    v2f p2l, q22l, q12l;  // left-shifted (element e-1)
    p2l.x = p2Ls;   p2l.y = p2_.x;
    q22l.x = q22Ls; q22l.y = q22_.x;
    q12l.x = q12Ls; q12l.y = q12_.x;

    const v2f divp = mD * p1_ + mR * p2_ - (mU * p1U + mL * p2l);
    const v2f un = (u_ + kTau * divp + kTau * f_) * kInv1pTau;
    ub_ = 2.f * un - u_;
    u_ = un;

    const v2f c1 = mD * q11_ + mR * q12_ - (mU * q11U + mL * q12l);
    const v2f c2 = mD * q12_ + mR * q22_ - (mU * q12U + mL * q22l);
    const v2f v1n = v1_ + kTau * (p1_ + c1);
    const v2f v2n = v2_ + kTau * (p2_ + c2);
    vb1_ = 2.f * v1n - v1_;
    v1_ = v1n;
    vb2_ = 2.f * v2n - v2_;
    v2_ = v2n;
  }

  // ---- store interior 16x32 (exact after 8 iters) ----
  if (r >= HALO && r < HALO + TILE_R && c >= HALO && c < HALO + TILE_C) {
#define STOREV(src, dst) *reinterpret_cast<v2f*>((dst) + base) = src;
    STOREV(u_, ug)
    if (t0 != NLAUNCH - 1) {  // ws is dead after the final launch
      STOREV(ub_, ubg)
      STOREV(v1_, v1g)
      STOREV(v2_, v2g)
      STOREV(vb1_, vb1g)
      STOREV(vb2_, vb2g)
      STOREV(p1_, p1g)
      STOREV(p2_, p2g)
      STOREV(q11_, q11g)
      STOREV(q22_, q22g)
      STOREV(q12_, q12g)
    }
#undef STOREV
  }
}

}  // namespace

extern "C" void kernel_launch(void* const* d_in, const int* in_sizes, int n_in,
                              void* d_out, int out_size, void* d_ws,
                              size_t ws_size, hipStream_t stream) {
  const float* f = (const float*)d_in[0];
  const float* rp = (const float*)d_in[1];  // [alpha0, alpha1]
  // d_in[2] is T = 128 (fixed; trip count must be static for graph capture).

  float* u = (float*)d_out;
  float* ws = (float*)d_ws;

  dim3 grid(256 / TILE_C, 256 / TILE_R, 2);  // 8 x 16 x 2 = 256 blocks
  for (int t = 0; t < NLAUNCH; ++t) {        // 16 launches x 8 iterations
    hipLaunchKernelGGL(tgv8_kernel, grid, dim3(NTHREADS), 0, stream, f, rp, u,
                       ws, t);
  }
}

// Round 13
// 253.712 us; speedup vs baseline: 1.3928x; 1.0306x over previous
//
#include <hip/hip_runtime.h>
#include <math.h>

// TGV-2 PDHG, B=2, H=W=256, T=128.
// R13 = R9 verbatim (best measured: 255.8us). R12's packed primal exchange
// (DS instr 17->13) measured NEUTRAL-to-worse (261.5) -> the kernel is not
// LDS-throughput-bound; residual is phase-convergence latency + ~5us/launch
// fixed cost. Design space mapped; every neighbor of this config measured or
// modeled worse:
//  - redundancy: 3.0 is the min for divisor-compatible tiles at <=1024 thr
//  - waves: 12 (6->12 gave only +6%; 3 waves is an occupancy floor, R11)
//  - HALO: 8 is the launch-count optimum (fixed ~5us vs work trade)
//  - persistent kernels: 4x regression (XCD coherence fences -> HBM refetch)
//  - batch-pairing in one block: scales with redundancy (R10)
// Config: 16 launches x 8 trapezoid iters, region 32x48 (tile 16x32, halo 8),
// 256 blocks (1/CU), 768 threads (12 waves), 1x2 strips, packed v_pk_f32
// math, 0/1 mask multipliers, rsq+min projection, vb1/vb2 interleaved LDS
// pair, init folded into launch 0, final launch stores only u.

namespace {

typedef float v2f __attribute__((ext_vector_type(2)));

constexpr int kN = 2 * 256 * 256;
constexpr float kTau = 0.28867513459481287f;  // 1/sqrt(12) (f32)
constexpr float kSigma = kTau;
constexpr float kInv1pTau = 1.0f / (1.0f + kTau);

constexpr int RR = 32;          // region rows (H)
constexpr int RC = 48;          // region cols (W)
constexpr int A = RR * RC;      // 1536 floats per LDS array
constexpr int PAD = 64;         // rim-overread safety pads (front/back)
constexpr int TILE_R = 16;
constexpr int TILE_C = 32;
constexpr int HALO = 8;         // = iterations per launch
constexpr int NLAUNCH = 128 / HALO;      // 16
constexpr int NTHREADS = RR * (RC / 2);  // 768 = 12 waves

__device__ __forceinline__ float4 ld4(const float* p) {
  return *reinterpret_cast<const float4*>(p);
}

// ws layout: 10 arrays of kN floats: ub, v1, v2, vb1, vb2, p1, p2, q11, q22, q12
__global__ __launch_bounds__(NTHREADS, 3) void tgv8_kernel(
    const float* __restrict__ f, const float* __restrict__ rp,
    float* __restrict__ ug, float* __restrict__ ws, int t0) {
  float* ubg = ws + 0 * kN;
  float* v1g = ws + 1 * kN;
  float* v2g = ws + 2 * kN;
  float* vb1g = ws + 3 * kN;
  float* vb2g = ws + 4 * kN;
  float* p1g = ws + 5 * kN;
  float* p2g = ws + 6 * kN;
  float* q11g = ws + 7 * kN;
  float* q22g = ws + 8 * kN;
  float* q12g = ws + 9 * kN;

  // LDS: ub (A) + vb-pair (2A) + p1,p2,q11,q22,q12 (5A) = 8A floats
  __shared__ __align__(16) float smem[PAD + 8 * A + PAD];
  float* ubS = smem + PAD;
  float* vbS = ubS + A;       // interleaved [vb1, vb2] per pixel, 2A floats
  float* p1S = vbS + 2 * A;
  float* p2S = p1S + A;
  float* q11S = p2S + A;
  float* q22S = q11S + A;
  float* q12S = q22S + A;

  const int tid = threadIdx.x;
  const int r = tid / 24;        // region row 0..31
  const int c = (tid % 24) * 2;  // region col (float2-aligned)
  const int rc = r * RC + c;

  const int gi = blockIdx.y * TILE_R + r - HALO;  // global row (may be OOB)
  const int gj = blockIdx.x * TILE_C + c - HALO;  // global col (even)
  const bool inImg = ((unsigned)gi < 256u) && ((unsigned)gj < 256u);
  const int base = blockIdx.z * 65536 + gi * 256 + gj;

  const float alpha0 = rp[0];
  const float alpha1 = rp[1];

  // ---- boundary masks as 0/1 multipliers (thread-constant) ----
  const float mD = (gi != 255) ? 1.f : 0.f;  // has down neighbor (H fwd)
  const float mU = (gi != 0) ? 1.f : 0.f;    // has up neighbor (H bwd)
  v2f mR, mL;
  mR.x = (gj + 0 != 255) ? 1.f : 0.f;
  mR.y = (gj + 1 != 255) ? 1.f : 0.f;
  mL.x = (gj != 0) ? 1.f : 0.f;
  mL.y = 1.f;

  // state: one packed v2f per field
  v2f u_, ub_, v1_, v2_, vb1_, vb2_, p1_, p2_, q11_, q22_, q12_, f_;

#define LOADV(dst, src) dst = *reinterpret_cast<const v2f*>((src) + base);
  if (inImg) {
    LOADV(f_, f)
    if (t0 == 0) {
      // PDHG initial state: u = ub = f, everything else zero.
      u_ = f_; ub_ = f_;
      v1_ = 0.f; v2_ = 0.f; vb1_ = 0.f; vb2_ = 0.f;
      p1_ = 0.f; p2_ = 0.f; q11_ = 0.f; q22_ = 0.f; q12_ = 0.f;
    } else {
      LOADV(u_, ug)
      LOADV(ub_, ubg)
      LOADV(v1_, v1g)
      LOADV(v2_, v2g)
      LOADV(vb1_, vb1g)
      LOADV(vb2_, vb2g)
      LOADV(p1_, p1g)
      LOADV(p2_, p2g)
      LOADV(q11_, q11g)
      LOADV(q22_, q22g)
      LOADV(q12_, q12g)
    }
  } else {
    f_ = 0.f; u_ = 0.f; ub_ = 0.f;
    v1_ = 0.f; v2_ = 0.f; vb1_ = 0.f; vb2_ = 0.f;
    p1_ = 0.f; p2_ = 0.f; q11_ = 0.f; q22_ = 0.f; q12_ = 0.f;
  }
#undef LOADV

  for (int t = 0; t < HALO; ++t) {
    // ---- publish dual halos: ub (b64), vb pair (b128) ----
    *reinterpret_cast<v2f*>(ubS + rc) = ub_;
    {
      float4 vp;
      vp.x = vb1_.x; vp.y = vb2_.x; vp.z = vb1_.y; vp.w = vb2_.y;
      *reinterpret_cast<float4*>(vbS + 2 * rc) = vp;
    }
    __syncthreads();

    // ---- dual ascent + projections ----
    const float ubX = ubS[rc + 2];  // right-edge scalar neighbor
    const v2f vbX = *reinterpret_cast<const v2f*>(vbS + 2 * (rc + 2));
    const v2f ubD = *reinterpret_cast<const v2f*>(ubS + rc + RC);
    const float4 vd = ld4(vbS + 2 * (rc + RC));
    v2f vb1D, vb2D;
    vb1D.x = vd.x; vb1D.y = vd.z;
    vb2D.x = vd.y; vb2D.y = vd.w;

    v2f ubr, vb1r, vb2r;  // right-shifted (element e+1)
    ubr.x = ub_.y;   ubr.y = ubX;
    vb1r.x = vb1_.y; vb1r.y = vbX.x;
    vb2r.x = vb2_.y; vb2r.y = vbX.y;

    // p update
    const v2f du1 = mD * (ubD - ub_);
    const v2f du2 = mR * (ubr - ub_);
    const v2f pn1 = p1_ + kSigma * (du1 - vb1_);
    const v2f pn2 = p2_ + kSigma * (du2 - vb2_);
    const v2f n2p = pn1 * pn1 + pn2 * pn2;
    v2f sp;
    sp.x = fminf(1.f, alpha1 * __builtin_amdgcn_rsqf(n2p.x));
    sp.y = fminf(1.f, alpha1 * __builtin_amdgcn_rsqf(n2p.y));
    p1_ = pn1 * sp;
    p2_ = pn2 * sp;

    // q update (e11, e22, e12)
    const v2f e11 = mD * (vb1D - vb1_);
    const v2f e22 = mR * (vb2r - vb2_);
    const v2f e12 = 0.5f * (mR * (vb1r - vb1_) + mD * (vb2D - vb2_));
    const v2f qn1 = q11_ + kSigma * e11;
    const v2f qn2 = q22_ + kSigma * e22;
    const v2f qn3 = q12_ + kSigma * e12;
    const v2f n2q = qn1 * qn1 + qn2 * qn2 + 2.f * (qn3 * qn3);
    v2f sq;
    sq.x = fminf(1.f, alpha0 * __builtin_amdgcn_rsqf(n2q.x));
    sq.y = fminf(1.f, alpha0 * __builtin_amdgcn_rsqf(n2q.y));
    q11_ = qn1 * sq;
    q22_ = qn2 * sq;
    q12_ = qn3 * sq;

    // ---- publish primal halos (new p, q) ----
    *reinterpret_cast<v2f*>(p1S + rc) = p1_;
    *reinterpret_cast<v2f*>(p2S + rc) = p2_;
    *reinterpret_cast<v2f*>(q11S + rc) = q11_;
    *reinterpret_cast<v2f*>(q22S + rc) = q22_;
    *reinterpret_cast<v2f*>(q12S + rc) = q12_;
    __syncthreads();

    // ---- primal descent + over-relaxation ----
    const v2f p1U = *reinterpret_cast<const v2f*>(p1S + rc - RC);
    const v2f q11U = *reinterpret_cast<const v2f*>(q11S + rc - RC);
    const v2f q12U = *reinterpret_cast<const v2f*>(q12S + rc - RC);
    const float p2Ls = p2S[rc - 1];   // left-edge scalar neighbors
    const float q22Ls = q22S[rc - 1];
    const float q12Ls = q12S[rc - 1];

    v2f p2l, q22l, q12l;  // left-shifted (element e-1)
    p2l.x = p2Ls;   p2l.y = p2_.x;
    q22l.x = q22Ls; q22l.y = q22_.x;
    q12l.x = q12Ls; q12l.y = q12_.x;

    const v2f divp = mD * p1_ + mR * p2_ - (mU * p1U + mL * p2l);
    const v2f un = (u_ + kTau * divp + kTau * f_) * kInv1pTau;
    ub_ = 2.f * un - u_;
    u_ = un;

    const v2f c1 = mD * q11_ + mR * q12_ - (mU * q11U + mL * q12l);
    const v2f c2 = mD * q12_ + mR * q22_ - (mU * q12U + mL * q22l);
    const v2f v1n = v1_ + kTau * (p1_ + c1);
    const v2f v2n = v2_ + kTau * (p2_ + c2);
    vb1_ = 2.f * v1n - v1_;
    v1_ = v1n;
    vb2_ = 2.f * v2n - v2_;
    v2_ = v2n;
  }

  // ---- store interior 16x32 (exact after 8 iters) ----
  if (r >= HALO && r < HALO + TILE_R && c >= HALO && c < HALO + TILE_C) {
#define STOREV(src, dst) *reinterpret_cast<v2f*>((dst) + base) = src;
    STOREV(u_, ug)
    if (t0 != NLAUNCH - 1) {  // ws is dead after the final launch
      STOREV(ub_, ubg)
      STOREV(v1_, v1g)
      STOREV(v2_, v2g)
      STOREV(vb1_, vb1g)
      STOREV(vb2_, vb2g)
      STOREV(p1_, p1g)
      STOREV(p2_, p2g)
      STOREV(q11_, q11g)
      STOREV(q22_, q22g)
      STOREV(q12_, q12g)
    }
#undef STOREV
  }
}

}  // namespace

extern "C" void kernel_launch(void* const* d_in, const int* in_sizes, int n_in,
                              void* d_out, int out_size, void* d_ws,
                              size_t ws_size, hipStream_t stream) {
  const float* f = (const float*)d_in[0];
  const float* rp = (const float*)d_in[1];  // [alpha0, alpha1]
  // d_in[2] is T = 128 (fixed; trip count must be static for graph capture).

  float* u = (float*)d_out;
  float* ws = (float*)d_ws;

  dim3 grid(256 / TILE_C, 256 / TILE_R, 2);  // 8 x 16 x 2 = 256 blocks
  for (int t = 0; t < NLAUNCH; ++t) {        // 16 launches x 8 iterations
    hipLaunchKernelGGL(tgv8_kernel, grid, dim3(NTHREADS), 0, stream, f, rp, u,
                       ws, t);
  }
}